// Round 1
// baseline (149.136 us; speedup 1.0000x reference)
//
#include <hip/hip_runtime.h>

// DispNetC correlation volume: out[b,d,h,w] = mean_c L[b,c,h,w]*R[b,c,h,w-d]
// for w>=d, else 0.  f32 in / f32 out.
//
// R6-R10 pinned at ~50us (2.7 TB/s delivery) across all staging schemes,
// warm or cold LLC. Invariant: per-(b,h) blocks read 512B segments on a
// 32KB stride -> 2 sectors/instr, L2/LLC bin-camping. This version: block
// owns an h-PAIR -> float4 loads are 1KB CONTIGUOUS (8 sectors/instr, 4x
// bin spread), 256 blocks (one tail-free round), 16 waves/CU. Lane-holds-4w
// data is transposed to the MFMA [w][c] layout via per-wave-private LDS
// scratch. Compute = R6's hardware-verified 26-tile band MFMA, x2 h.
//
// R11: resubmission of the identical kernel — previous bench run died to an
// infrastructure failure (container failed twice), no counters produced.
// Re-establishing baseline before the next theory-driven edit.

typedef __attribute__((ext_vector_type(8))) short short8;   // MFMA A/B frag
typedef __attribute__((ext_vector_type(4))) float floatx4;  // MFMA C/D frag

#define NB 8
#define NC 256
#define NH 64
#define NWD 128
#define ND 40
#define KC 64          // channels per chunk; 4 chunks
// s_waitcnt imm: vm[3:0] | exp[6:4]=7 | lgkm[11:8] | vm[5:4]@[15:14]
#define WCNT(vm, lgkm) (((vm) & 15) | (((vm) >> 4) << 14) | (7 << 4) | ((lgkm) << 8))

// LDS map (bytes):
//   Lbuf [hh][w][KC] u16 swizzled : 0      (32 KB)
//   Rbuf same                     : 32768  (32 KB)
//   scratch, per-wave 8*132 f32   : 65536 + wv*4224  (67.6 KB)
// total 133120 B -> 1 block/CU, 16 waves.

__global__ __launch_bounds__(1024, 4) void corr_hpair(
    const float* __restrict__ Lg,
    const float* __restrict__ Rg,
    float* __restrict__ out)
{
  __shared__ __align__(16) unsigned char smem[65536 + 16 * 4224];

  const int blk  = blockIdx.x;
  const int b    = blk >> 5;       // 8 b
  const int h2   = blk & 31;       // h-pair index; h = 2*h2 + hh
  const int tid  = threadIdx.x;
  const int lane = tid & 63;
  const int wv   = tid >> 6;       // 0..15
  const int m    = lane & 15;
  const int q    = lane >> 4;

  const size_t HW    = (size_t)NH * NWD;
  const size_t gbase = (size_t)b * NC * HW + (size_t)(h2 * 2) * NWD;

  float* scr = (float*)(smem + 65536 + wv * 4224);   // [8][132] f32

  floatx4 acc[4];
  #pragma unroll
  for (int i = 0; i < 4; ++i) acc[i] = (floatx4){0.f, 0.f, 0.f, 0.f};

  for (int chunk = 0; chunk < 4; ++chunk) {
    __syncthreads();  // prev MFMA frag reads done before finals overwrite

    // ---- stage: 2 units/wave; unit = one array x 4 channels x both h ----
    #pragma unroll
    for (int uu = 0; uu < 2; ++uu) {
      const int ug  = wv * 2 + uu;     // 0..31
      const int arr = ug & 1;          // 0 = L, 1 = R
      const int cq  = ug >> 1;         // c-quad 0..15
      const int c0  = chunk * KC + cq * 4;
      const int gu  = cq >> 1;         // 8-c group 0..7
      const int su  = cq & 1;          // which b64 half of the group
      const float* src = arr ? Rg : Lg;

      // 4 contiguous-1KB loads: rows (c0+i, h0) and (c0+i, h1)
      float4 v[4];
      #pragma unroll
      for (int i = 0; i < 4; ++i) {
        const float* gp = src + gbase + (size_t)(c0 + i) * HW
                        + (lane >> 5) * NWD + 4 * (lane & 31);
        v[i] = *(const float4*)gp;
      }
      // scratch write: row = 2*c' + hh, padded stride 132 (2-way free)
      #pragma unroll
      for (int i = 0; i < 4; ++i)
        *(float4*)(scr + (2 * i + (lane >> 5)) * 132 + 4 * (lane & 31)) = v[i];
      __builtin_amdgcn_s_waitcnt(WCNT(63, 0));  // scratch visible to own wave

      // gather 4 c per (hh,w), pack bf16 (round-half-up), b64 to final
      unsigned short* fin = (unsigned short*)(smem + arr * 32768);
      #pragma unroll
      for (int t = 0; t < 4; ++t) {
        const int hh = t >> 1;
        const int w  = lane + (t & 1) * 64;
        float f[4];
        #pragma unroll
        for (int c1 = 0; c1 < 4; ++c1)
          f[c1] = scr[(2 * c1 + hh) * 132 + w];
        const unsigned int lo =
            ((__float_as_uint(f[0]) + 0x8000u) >> 16) |
            ((__float_as_uint(f[1]) + 0x8000u) & 0xFFFF0000u);
        const unsigned int hi =
            ((__float_as_uint(f[2]) + 0x8000u) >> 16) |
            ((__float_as_uint(f[3]) + 0x8000u) & 0xFFFF0000u);
        // u16 index: hh*8192 + w*64 + ((gu ^ (w&7))<<3) + 4*su  (swizzled)
        *(uint2*)(fin + hh * 8192 + w * 64 + ((gu ^ (w & 7)) << 3) + 4 * su) =
            make_uint2(lo, hi);
      }
      __builtin_amdgcn_s_waitcnt(WCNT(63, 0));  // gathers done before scratch reuse
    }
    __syncthreads();

    // ---- MFMA: 52 instances (2h x 26 band tiles) over 16 waves ----
    const unsigned short* Lb = (const unsigned short*)smem;
    const unsigned short* Rb = (const unsigned short*)(smem + 32768);
    #pragma unroll
    for (int ks2 = 0; ks2 < 2; ++ks2) {        // two K=32 steps per chunk
      #pragma unroll
      for (int li = 0; li < 4; ++li) {
        const int inst = wv + (li << 4);
        if (inst >= 52) break;
        const int hh   = (inst >= 26) ? 1 : 0;
        const int tile = inst - hh * 26;
        const int i  = (tile < 8) ? tile : (tile < 15) ? tile - 8
                     : (tile < 21) ? tile - 15 : tile - 21;
        const int k  = (tile < 8) ? 0 : (tile < 15) ? 1 : (tile < 21) ? 2 : 3;
        const int j  = i + k;
        const int g  = ks2 * 4 + q;            // c = 32*ks2 + 8*q + e
        const int ra = 16 * i + m;             // w' row for A (from R)
        const int rb = 16 * j + m;             // w  col for B (from L)
        const short8 av =
            *(const short8*)(Rb + hh * 8192 + ra * 64 + ((g ^ (ra & 7)) << 3));
        const short8 bv =
            *(const short8*)(Lb + hh * 8192 + rb * 64 + ((g ^ (rb & 7)) << 3));
        acc[li] = __builtin_amdgcn_mfma_f32_16x16x32_bf16(av, bv, acc[li], 0, 0, 0);
      }
    }
  }

  // ---- epilogue: D layout col=lane&15 (w in tile j), row=q*4+r (w' in tile i) ----
  #pragma unroll
  for (int li = 0; li < 4; ++li) {
    const int inst = wv + (li << 4);
    if (inst >= 52) break;
    const int hh   = (inst >= 26) ? 1 : 0;
    const int tile = inst - hh * 26;
    const int i  = (tile < 8) ? tile : (tile < 15) ? tile - 8
                 : (tile < 21) ? tile - 15 : tile - 21;
    const int k  = (tile < 8) ? 0 : (tile < 15) ? 1 : (tile < 21) ? 2 : 3;
    const int j  = i + k;
    const int h  = h2 * 2 + hh;
    const int w  = 16 * j + m;
    #pragma unroll
    for (int r = 0; r < 4; ++r) {
      const int wp = 16 * i + q * 4 + r;
      const int d  = w - wp;
      if (d >= 0 && d < ND)
        out[(((size_t)b * ND + d) * NH + h) * NWD + w] = acc[li][r] * 0.00390625f;
    }
  }

  // ---- zero-fill the w<d triangle for both h (d_out poisoned each launch) ----
  for (int t = tid; t < 2 * ND * ND; t += 1024) {
    const int hh = (t >= ND * ND) ? 1 : 0;
    const int tt = t - hh * ND * ND;
    const int d  = tt / ND;
    const int w  = tt - d * ND;
    if (w < d)
      out[(((size_t)b * ND + d) * NH + (h2 * 2 + hh)) * NWD + w] = 0.0f;
  }
}

extern "C" void kernel_launch(void* const* d_in, const int* in_sizes, int n_in,
                              void* d_out, int out_size, void* d_ws, size_t ws_size,
                              hipStream_t stream) {
  corr_hpair<<<dim3(256), dim3(1024), 0, stream>>>(
      (const float*)d_in[0], (const float*)d_in[1], (float*)d_out);
}